// Round 1
// baseline (106.633 us; speedup 1.0000x reference)
//
#include <hip/hip_runtime.h>

// TiedCirculantSpectralFilter: B=512, D=1024, P=64, K=16, L_S=16
// out[b,:] = hk after 16 steps of:
//   hp <- hp - (1/16) * A * hp,   A = score[:64,:64]
//   hk <- hk + (1/16) * C * hp,   C = score[64:80,:64]
// score[m,n] = sum_d gamma[d] X[b,d,m] X[b,d,n] / 64

namespace {
constexpr int kB  = 512;
constexpr int kD  = 1024;
constexpr int kPK = 80;   // P+K
constexpr int kP  = 64;
constexpr int kK  = 16;
constexpr int kLS = 16;
constexpr int kTD = 64;                    // d-rows per LDS tile
constexpr int kNT = kD / kTD;              // 16 tiles
constexpr int kThreads = 320;              // 5 waves; 20 m-chunks x 16 n-chunks
constexpr int kTileF4 = kTD * kPK / 4;     // 1280 float4 per tile
constexpr int kF4PerThread = kTileF4 / kThreads;  // 4

__global__ void __launch_bounds__(kThreads)
tcsf_kernel(const float* __restrict__ X, const float* __restrict__ y,
            const float* __restrict__ gamma, float* __restrict__ out) {
  // LDS layout (floats):
  //   [0,1024)              : gamma (whole vector, loaded once)
  //   [1024, 1024+5120)     : raw X tile  [64][80]
  //   [6144, 6144+5120)     : gamma-weighted X tile [64][80]
  // phase 2 (aliases the tiles, after barrier):
  //   [1024, 1024+80*65)    : G, padded stride 65
  //   [+0, +64)             : hp
  __shared__ float smem[11264];  // 45,056 B -> 2 blocks/CU
  float* gs = smem;
  float4* Xs4 = reinterpret_cast<float4*>(smem + 1024);
  float4* Xw4 = reinterpret_cast<float4*>(smem + 1024 + kTD * kPK);

  const int t = threadIdx.x;
  const int b = blockIdx.x;

  // gamma -> LDS once
  for (int i = t; i < kD; i += kThreads) gs[i] = gamma[i];
  __syncthreads();

  const int c = t & 15;   // n-chunk: n = 4c..4c+3   (covers 0..63)
  const int a = t >> 4;   // m-chunk: m = 4a..4a+3   (covers 0..79)

  float acc[4][4];
#pragma unroll
  for (int i = 0; i < 4; ++i)
#pragma unroll
    for (int j = 0; j < 4; ++j) acc[i][j] = 0.f;

  const float4* Xg = reinterpret_cast<const float4*>(X + (size_t)b * kD * kPK);

  // prologue: prefetch tile 0
  float4 v[kF4PerThread];
  float gv[kF4PerThread];
#pragma unroll
  for (int i = 0; i < kF4PerThread; ++i) {
    const int q = t + kThreads * i;        // flat float4 index in tile
    v[i] = Xg[q];
    gv[i] = gs[q / 20];                    // d-row of this float4 (80 floats = 20 f4/row)
  }

  for (int tile = 0; tile < kNT; ++tile) {
    __syncthreads();  // previous compute done with LDS tile
#pragma unroll
    for (int i = 0; i < kF4PerThread; ++i) {
      const int q = t + kThreads * i;
      Xs4[q] = v[i];
      float4 w;
      w.x = v[i].x * gv[i]; w.y = v[i].y * gv[i];
      w.z = v[i].z * gv[i]; w.w = v[i].w * gv[i];
      Xw4[q] = w;
    }
    __syncthreads();
    if (tile + 1 < kNT) {  // prefetch next tile; latency hides under compute
#pragma unroll
      for (int i = 0; i < kF4PerThread; ++i) {
        const int q = t + kThreads * i;
        v[i] = Xg[(tile + 1) * kTileF4 + q];
        gv[i] = gs[(tile + 1) * kTD + q / 20];
      }
    }
#pragma unroll 2
    for (int dd = 0; dd < kTD; ++dd) {
      const float4 xm = Xw4[dd * 20 + a];  // weighted, m side
      const float4 xn = Xs4[dd * 20 + c];  // raw, n side
      const float xmv[4] = {xm.x, xm.y, xm.z, xm.w};
      const float xnv[4] = {xn.x, xn.y, xn.z, xn.w};
#pragma unroll
      for (int i = 0; i < 4; ++i)
#pragma unroll
        for (int j = 0; j < 4; ++j)
          acc[i][j] = fmaf(xmv[i], xnv[j], acc[i][j]);
    }
  }

  __syncthreads();  // done with X tiles; reuse their LDS for G
  float* Gl = smem + 1024;          // [80][65] padded
  float* hp = Gl + kPK * 65;        // [64]
  constexpr float invP = 1.0f / kP;
#pragma unroll
  for (int i = 0; i < 4; ++i)
#pragma unroll
    for (int j = 0; j < 4; ++j)
      Gl[(4 * a + i) * 65 + (4 * c + j)] = acc[i][j] * invP;

  if (t < kP) hp[t] = y[b * kP + t];
  __syncthreads();

  // phase 2: 16 steps, 4 threads per row (80 rows x 4 = 320)
  const int m = t >> 2;
  const int part = t & 3;
  const float* Grow = Gl + m * 65 + part * 16;
  const float* hpp = hp + part * 16;
  float hk = 0.f;
  constexpr float invL = 1.0f / kLS;
  for (int s = 0; s < kLS; ++s) {
    float d0 = 0.f, d1 = 0.f, d2 = 0.f, d3 = 0.f;
#pragma unroll
    for (int i = 0; i < 16; i += 4) {
      d0 = fmaf(Grow[i + 0], hpp[i + 0], d0);
      d1 = fmaf(Grow[i + 1], hpp[i + 1], d1);
      d2 = fmaf(Grow[i + 2], hpp[i + 2], d2);
      d3 = fmaf(Grow[i + 3], hpp[i + 3], d3);
    }
    float dot = (d0 + d1) + (d2 + d3);
    dot += __shfl_xor(dot, 1);
    dot += __shfl_xor(dot, 2);
    __syncthreads();  // all reads of hp for this step complete
    if (part == 0) {
      if (m < kP) hp[m] -= invL * dot;   // unique writer per m
      else        hk   += invL * dot;
    }
    __syncthreads();  // hp update visible for next step
  }
  if (part == 0 && m >= kP) out[b * kK + (m - kP)] = hk;
}

}  // namespace

extern "C" void kernel_launch(void* const* d_in, const int* in_sizes, int n_in,
                              void* d_out, int out_size, void* d_ws, size_t ws_size,
                              hipStream_t stream) {
  const float* X     = (const float*)d_in[0];  // [512,1024,80]
  const float* y     = (const float*)d_in[1];  // [512,64]
  const float* gamma = (const float*)d_in[2];  // [1024]
  float* out = (float*)d_out;                  // [512,16]
  tcsf_kernel<<<dim3(kB), dim3(kThreads), 0, stream>>>(X, y, gamma, out);
}

// Round 3
// 39.765 us; speedup vs baseline: 2.6816x; 2.6816x over previous
//
#include <hip/hip_runtime.h>

// TiedCirculantSpectralFilter: B=512, D=1024, P=64, K=16, L_S=16
// Gram G[m,n] = sum_d X[d,m] * (gamma_d * X[d,n]) / 64  via bf16 MFMA,
// then 16-step iteration:
//   hp <- hp - (1/16) A hp   (A = G[:64,:64])
//   hk <- hk + (1/16) C hp   (C = G[64:80,:64])

namespace {
typedef __attribute__((ext_vector_type(8))) short bf16x8;
typedef __attribute__((ext_vector_type(4))) float f32x4;
typedef __attribute__((ext_vector_type(4))) float fv4;
typedef __attribute__((ext_vector_type(2))) unsigned uv2;

constexpr int kB  = 512;
constexpr int kD  = 1024;
constexpr int kP  = 64;
constexpr int kKK = 16;   // K tail rows
constexpr int kLS = 16;
constexpr int kThreads = 320;           // 5 waves
constexpr int kKc = 64;                 // d-rows per chunk
constexpr int kNC = kD / kKc;           // 16 chunks

// LDS byte layout
constexpr int TB    = 4096;             // tiles base (gamma f32[1024] at 0)
constexpr int ASZ   = 80 * 64 * 2;      // 10240 B : A tile [80 m][64 k] bf16 (swizzled)
constexpr int BSZ   = 64 * 64 * 2;      // 8192 B  : B tile [64 n][64 k] bf16 (swizzled, gamma-weighted)
constexpr int BUFSZ = ASZ + BSZ;        // 18432
constexpr int LDS_BYTES = TB + 2 * BUFSZ;  // 40960

__device__ __forceinline__ unsigned short bf16_bits(float x) {
  unsigned u = __builtin_bit_cast(unsigned, x);
  u += 0x7fffu + ((u >> 16) & 1u);   // round-to-nearest-even
  return (unsigned short)(u >> 16);
}
__device__ __forceinline__ unsigned bpack(float lo, float hi) {
  return (unsigned)bf16_bits(lo) | ((unsigned)bf16_bits(hi) << 16);
}

__global__ void __launch_bounds__(kThreads)
tcsf_kernel(const float* __restrict__ X, const float* __restrict__ y,
            const float* __restrict__ gamma, float* __restrict__ out) {
  __shared__ __align__(16) char smem[LDS_BYTES];
  float* gs = reinterpret_cast<float*>(smem);

  const int t = threadIdx.x;
  const int b = blockIdx.x;
  const int l = t & 63;
  const int w = t >> 6;            // wave 0..4 -> m-rows 16w..16w+15

  // gamma -> LDS
  for (int i = t; i < kD; i += kThreads) gs[i] = gamma[i];

  const fv4* Xg = reinterpret_cast<const fv4*>(X) + (size_t)b * (kD * 80 / 4);

  // staging decomposition: thread t handles k = 4*kt + i (i=0..3), m = 4*ct + j (j=0..3)
  const int ct = t % 20;           // m-quad
  const int kt = t / 20;           // k-quad (0..15)

  f32x4 acc[4];
#pragma unroll
  for (int nt = 0; nt < 4; ++nt) acc[nt] = (f32x4)(0.f);

  fv4 v0, v1, v2, v3;
  fv4 g4;

  __syncthreads();  // gamma visible

  // ---- prologue: load + stage chunk 0 into buf 0 ----
  {
    const int base = (0 * kKc + 4 * kt) * 20 + ct;
    v0 = Xg[base]; v1 = Xg[base + 20]; v2 = Xg[base + 40]; v3 = Xg[base + 60];
    g4 = *reinterpret_cast<const fv4*>(gs + 0 * kKc + 4 * kt);
    char* Ab = smem + TB;
    char* Bb = Ab + ASZ;
#pragma unroll
    for (int j = 0; j < 4; ++j) {
      const int m = 4 * ct + j;
      const int rowo = m * 128;
      const int col = (8 * kt) ^ ((m & 7) << 4);
      uv2 wa; wa.x = bpack(v0[j], v1[j]); wa.y = bpack(v2[j], v3[j]);
      *reinterpret_cast<uv2*>(Ab + rowo + col) = wa;
      if (ct < 16) {
        uv2 wb; wb.x = bpack(g4[0] * v0[j], g4[1] * v1[j]);
        wb.y = bpack(g4[2] * v2[j], g4[3] * v3[j]);
        *reinterpret_cast<uv2*>(Bb + rowo + col) = wb;
      }
    }
  }

  // fragment read addressing (constant per thread)
  const int rA = 16 * w + (l & 15);
  const int colb = (l >> 4) * 16;
  const int fswz = (l & 7) << 4;   // rA&7 == l&7, rB&7 == l&7

  // ---- main loop over 16 chunks, double-buffered ----
  for (int c = 0; c < kNC; ++c) {
    if (c + 1 < kNC) {  // issue next-chunk loads early; latency hides under compute
      const int base = ((c + 1) * kKc + 4 * kt) * 20 + ct;
      v0 = Xg[base]; v1 = Xg[base + 20]; v2 = Xg[base + 40]; v3 = Xg[base + 60];
      g4 = *reinterpret_cast<const fv4*>(gs + (c + 1) * kKc + 4 * kt);
    }
    __syncthreads();  // buf[c&1] staging complete
    {
      const char* Ab = smem + TB + (c & 1) * BUFSZ;
      const char* Bb = Ab + ASZ;
#pragma unroll
      for (int ks = 0; ks < 2; ++ks) {
        const int cb = ks * 64 + colb;
        const bf16x8 a = *reinterpret_cast<const bf16x8*>(Ab + rA * 128 + (cb ^ fswz));
#pragma unroll
        for (int nt = 0; nt < 4; ++nt) {
          const bf16x8 bb = *reinterpret_cast<const bf16x8*>(
              Bb + (16 * nt + (l & 15)) * 128 + (cb ^ fswz));
          acc[nt] = __builtin_amdgcn_mfma_f32_16x16x32_bf16(a, bb, acc[nt], 0, 0, 0);
        }
      }
    }
    __syncthreads();  // all waves done reading buf[(c+1)&1] (from iter c-1)
    if (c + 1 < kNC) {
      char* Ab = smem + TB + ((c + 1) & 1) * BUFSZ;
      char* Bb = Ab + ASZ;
#pragma unroll
      for (int j = 0; j < 4; ++j) {
        const int m = 4 * ct + j;
        const int rowo = m * 128;
        const int col = (8 * kt) ^ ((m & 7) << 4);
        uv2 wa; wa.x = bpack(v0[j], v1[j]); wa.y = bpack(v2[j], v3[j]);
        *reinterpret_cast<uv2*>(Ab + rowo + col) = wa;
        if (ct < 16) {
          uv2 wb; wb.x = bpack(g4[0] * v0[j], g4[1] * v1[j]);
          wb.y = bpack(g4[2] * v2[j], g4[3] * v3[j]);
          *reinterpret_cast<uv2*>(Bb + rowo + col) = wb;
        }
      }
    }
  }
  // loop exits right after a barrier; all MFMA reads done -> reuse tile LDS for G

  // ---- G -> LDS ----
  // C/D layout (m89): col = lane&15, row = (lane>>4)*4 + reg
  float* Gl = reinterpret_cast<float*>(smem + TB);  // [80][65] padded
  float* hp = Gl + 80 * 65;                         // [64]
  constexpr float invP = 1.0f / 64.0f;
#pragma unroll
  for (int nt = 0; nt < 4; ++nt)
#pragma unroll
    for (int r = 0; r < 4; ++r)
      Gl[(16 * w + (l >> 4) * 4 + r) * 65 + 16 * nt + (l & 15)] = acc[nt][r] * invP;

  if (t < kP) hp[t] = y[b * kP + t];
  __syncthreads();

  // ---- phase 2: 16 steps, 4 threads per row (80 rows x 4 = 320) ----
  const int m = t >> 2;
  const int part = t & 3;
  const float* Grow = Gl + m * 65 + part * 16;
  const float* hpp = hp + part * 16;
  float hk = 0.f;
  constexpr float invL = 1.0f / kLS;
  for (int s = 0; s < kLS; ++s) {
    float d0 = 0.f, d1 = 0.f, d2 = 0.f, d3 = 0.f;
#pragma unroll
    for (int i = 0; i < 16; i += 4) {
      d0 = fmaf(Grow[i + 0], hpp[i + 0], d0);
      d1 = fmaf(Grow[i + 1], hpp[i + 1], d1);
      d2 = fmaf(Grow[i + 2], hpp[i + 2], d2);
      d3 = fmaf(Grow[i + 3], hpp[i + 3], d3);
    }
    float dot = (d0 + d1) + (d2 + d3);
    dot += __shfl_xor(dot, 1);
    dot += __shfl_xor(dot, 2);
    __syncthreads();
    if (part == 0) {
      if (m < kP) hp[m] -= invL * dot;
      else        hk   += invL * dot;
    }
    __syncthreads();
  }
  if (part == 0 && m >= kP) out[b * kKK + (m - kP)] = hk;
}

}  // namespace

extern "C" void kernel_launch(void* const* d_in, const int* in_sizes, int n_in,
                              void* d_out, int out_size, void* d_ws, size_t ws_size,
                              hipStream_t stream) {
  const float* X     = (const float*)d_in[0];  // [512,1024,80]
  const float* y     = (const float*)d_in[1];  // [512,64]
  const float* gamma = (const float*)d_in[2];  // [1024]
  float* out = (float*)d_out;                  // [512,16]
  tcsf_kernel<<<dim3(kB), dim3(kThreads), 0, stream>>>(X, y, gamma, out);
}